// Round 7
// baseline (412.202 us; speedup 1.0000x reference)
//
#include <hip/hip_runtime.h>
#include <math.h>

#define D_    256
#define H_    256
#define R_    8
#define NINIT 8192
#define LL    16
#define MM    4096
#define NTOT  (NINIT + LL*MM)   // 73728
#define TB    16                // nodes per MFMA tile/block
#define MP    (MM + R_*TB)      // 4224 padded slots per layer
#define NB    (MP/TB)           // 264 blocks per layer
#define KS1   16                // K-steps GEMM1 (512/32)
#define KS2   8                 // K-steps GEMM2 (256/32)
#define NT    16                // n-tiles (256/16)

#define EMB_BLKS (NINIT*64/256)        // 2048
#define PK1_BLKS (R_*KS1*NT*64/256)    // 512
#define PK2_BLKS (R_*KS2*NT*64/256)    // 256
#define PREP_BLKS (LL + EMB_BLKS + PK1_BLKS + PK2_BLKS)
#define NPART (LL*NB + EMB_BLKS)       // 6272 partial slots (6 floats each)

typedef __attribute__((ext_vector_type(8))) short short8;
typedef __attribute__((ext_vector_type(4))) float f32x4;

__device__ __forceinline__ uint bf16h(float f) {           // f32 -> bf16 bits (RNE)
    uint u = __float_as_uint(f);
    return (u + 0x7fffu + ((u >> 16) & 1u)) >> 16;
}
__device__ __forceinline__ float bf16f(uint h) { return __uint_as_float(h << 16); }

// BCE partial terms for one node, given val (pre-sigmoid logit)
__device__ __forceinline__ void bce_terms(float val, float lab, float p, float ng,
                                          float* A, float* B, float* pOK, float* nOK,
                                          float* tp, float* tn) {
    float tot = p + ng;
    float target = p / fmaxf(tot, 1e-8f);
    float ls  = (val >= 0.f) ? -log1pf(expf(-val)) : (val  - log1pf(expf( val)));
    float lns = (val <= 0.f) ? -log1pf(expf( val)) : (-val - log1pf(expf(-val)));
    *A = lab*tot*target*ls;
    *B = lab*tot*(1.f - target)*lns;
    *pOK = (val >= 0.f) ? lab*p : 0.f;
    *nOK = (val <  0.f) ? lab*ng : 0.f;
    *tp = p*lab; *tn = ng*lab;
}

// ---------------- prep bodies ----------------
__device__ void sort_body(int l, int t, const int* __restrict__ rule,
                          int* __restrict__ sorted) {
    __shared__ int hist[R_], cursor[R_];
    if (t < R_) hist[t] = 0;
    __syncthreads();
    for (int m = t; m < MM; m += 256) atomicAdd(&hist[rule[l*MM + m]], 1);
    __syncthreads();
    if (t == 0) {
        int off = 0;
        for (int r = 0; r < R_; r++) { cursor[r] = off; off += ((hist[r] + TB - 1)/TB)*TB; }
    }
    for (int m = t; m < MP; m += 256) sorted[l*MP + m] = -1;
    __syncthreads();
    for (int m = t; m < MM; m += 256) {
        int r = rule[l*MM + m];
        int pos = atomicAdd(&cursor[r], 1);
        sorted[l*MP + pos] = m;
    }
}

// embed + fused eval for init nodes (one wave = one node; block = 4 nodes)
__device__ void embed_body(int b, int t, const float* __restrict__ itab,
                           const float* __restrict__ stab,
                           const int* __restrict__ thax, const int* __restrict__ sine,
                           float* __restrict__ store,
                           const float* __restrict__ w_eval, const float* __restrict__ b_eval,
                           const float* __restrict__ t_eval, const float* __restrict__ pt,
                           const float* __restrict__ pos, const float* __restrict__ neg,
                           const int* __restrict__ labeled, float* __restrict__ partials) {
    __shared__ float ered[4][6];
    int gid = b*256 + t;
    int n = gid >> 6, d = (gid & 63) << 2;
    int th = thax[n], si = sine[n];
    const float4 a = *(const float4*)&itab[th*D_ + d];
    const float4 bb = *(const float4*)&stab[si*D_ + d];
    float4 o; o.x = a.x+bb.x; o.y = a.y+bb.y; o.z = a.z+bb.z; o.w = a.w+bb.w;
    *(float4*)&store[(size_t)n*D_ + d] = o;
    // dot with w_eval
    const float4 we = *(const float4*)&w_eval[d];
    float pv = o.x*we.x + o.y*we.y + o.z*we.z + o.w*we.w;
    #pragma unroll
    for (int off = 32; off > 0; off >>= 1) pv += __shfl_xor(pv, off);
    int wvid = t >> 6;
    if ((t & 63) == 0) {
        float val = pv + b_eval[0] + pt[0]*t_eval[0];
        float A, B, pOK, nOK, tp, tn;
        bce_terms(val, (float)labeled[n], pos[n], neg[n], &A, &B, &pOK, &nOK, &tp, &tn);
        ered[wvid][0]=A; ered[wvid][1]=B; ered[wvid][2]=pOK;
        ered[wvid][3]=nOK; ered[wvid][4]=tp; ered[wvid][5]=tn;
    }
    __syncthreads();
    if (t < 6) partials[((size_t)LL*NB + b)*6 + t] =
        ered[0][t] + ered[1][t] + ered[2][t] + ered[3][t];
}

// Ph[((r*KSn + ks)*NT + nt)*64 + lane][j] = bf16(W[r][ks*32 + (lane>>4)*8 + j][nt*16 + (lane&15)])
__device__ void pack_body(int gid, const float* __restrict__ W,
                          ushort* __restrict__ Ph, int KSn) {
    int lane = gid & 63;
    int nt   = (gid >> 6) & 15;
    int ks   = (gid >> 10) % KSn;
    int r    = gid / (1024*KSn);
    int K = KSn*32;
    int k0 = ks*32 + (lane >> 4)*8;
    int c  = nt*16 + (lane & 15);
    const float* src = W + ((size_t)r*K + k0)*256 + c;
    uint h[8];
    #pragma unroll
    for (int j = 0; j < 8; j++) h[j] = bf16h(src[(size_t)j*256]);
    size_t o = (size_t)gid*8;
    *(uint4*)&Ph[o] = make_uint4(h[0]|(h[1]<<16), h[2]|(h[3]<<16), h[4]|(h[5]<<16), h[6]|(h[7]<<16));
}

__global__ __launch_bounds__(256) void prep_kernel(
        const int* __restrict__ drule, int* __restrict__ sorted,
        const float* __restrict__ itab, const float* __restrict__ stab,
        const int* __restrict__ thax, const int* __restrict__ sine,
        float* __restrict__ store,
        const float* __restrict__ W1, ushort* __restrict__ P1h,
        const float* __restrict__ W2, ushort* __restrict__ P2h,
        const float* __restrict__ w_eval, const float* __restrict__ b_eval,
        const float* __restrict__ t_eval, const float* __restrict__ pt,
        const float* __restrict__ pos, const float* __restrict__ neg,
        const int* __restrict__ labeled, float* __restrict__ partials) {
    int b = blockIdx.x, t = threadIdx.x;
    if (b < LL) {
        sort_body(b, t, drule, sorted);
    } else if (b < LL + EMB_BLKS) {
        embed_body(b - LL, t, itab, stab, thax, sine, store,
                   w_eval, b_eval, t_eval, pt, pos, neg, labeled, partials);
    } else if (b < LL + EMB_BLKS + PK1_BLKS) {
        pack_body((b - LL - EMB_BLKS)*256 + t, W1, P1h, KS1);
    } else {
        pack_body((b - LL - EMB_BLKS - PK1_BLKS)*256 + t, W2, P2h, KS2);
    }
}

// ---------------- one DAG layer + fused eval ----------------
// 16-node tile, 16 waves, 1 n-tile per wave; weights hi-only, activations split-bf16.
// All 24 weight fragments preloaded into registers BEFORE the gather so the single
// barrier waits on max(gather, weight stream) instead of their sum (T14).
__global__ __launch_bounds__(1024) void layer_kernel(float* __restrict__ store,
        const int* __restrict__ sorted, const int* __restrict__ rule,
        const int* __restrict__ parents,
        const ushort* __restrict__ P1h, const ushort* __restrict__ P2h,
        const float* __restrict__ b1, const float* __restrict__ t1,
        const float* __restrict__ b2, const float* __restrict__ pt,
        const float* __restrict__ w_eval, const float* __restrict__ b_eval,
        const float* __restrict__ t_eval,
        const float* __restrict__ pos, const float* __restrict__ neg,
        const int* __restrict__ labeled, float* __restrict__ partials, int l) {
    __shared__ ushort Xh[TB*512], Xl[TB*512];   // 16 rows x 512 bf16 hi/lo, swizzled
    __shared__ ushort Hh[TB*256], Hl[TB*256];
    __shared__ int idx_s[TB];
    __shared__ float vred[TB][17];
    const int t = threadIdx.x, lane = t & 63, wv = t >> 6;   // wv = 0..15
    const int base = l*MP + blockIdx.x*TB;
    const int idx0 = sorted[base];
    if (idx0 < 0) {                              // fully-padded tail tile
        if (t < 6) partials[((size_t)l*NB + blockIdx.x)*6 + t] = 0.f;
        return;
    }
    const int r = rule[l*MM + idx0];
    const int crow = lane & 15, kg = lane >> 4;
    const int col = wv*16 + crow;
    const float tw = pt[1];
    const float bev = b_eval[0] + pt[0]*t_eval[0];
    const float bb1 = b1[r*H_ + col] + tw * t1[r*H_ + col];
    const float bb2 = b2[r*D_ + col];
    const float we  = w_eval[col];

    // ---- issue ALL weight-fragment loads (fills vmem queue; drains at the barrier) ----
    const short8* B1hp = (const short8*)P1h + ((size_t)r*KS1*NT + wv)*64 + lane;
    const short8* B2hp = (const short8*)P2h + ((size_t)r*KS2*NT + wv)*64 + lane;
    short8 b1r[KS1], b2r[KS2];
    #pragma unroll
    for (int ks = 0; ks < KS1; ks++) b1r[ks] = B1hp[(size_t)ks*NT*64];
    #pragma unroll
    for (int ks = 0; ks < KS2; ks++) b2r[ks] = B2hp[(size_t)ks*NT*64];

    // ---- gather row wv (2 parent halves, float4/lane), convert, swizzled LDS write ----
    const int idxr = sorted[base + wv];
    if (lane == 0) idx_s[wv] = idxr;
    #pragma unroll
    for (int half = 0; half < 2; half++) {
        float4 v = make_float4(0.f, 0.f, 0.f, 0.f);
        if (idxr >= 0) {
            int p = parents[(l*MM + idxr)*2 + half];
            v = *(const float4*)&store[(size_t)p*D_ + lane*4];
        }
        uint h0 = bf16h(v.x), h1 = bf16h(v.y), h2 = bf16h(v.z), h3 = bf16h(v.w);
        uint l0 = bf16h(v.x - bf16f(h0)), l1 = bf16h(v.y - bf16f(h1));
        uint l2 = bf16h(v.z - bf16f(h2)), l3 = bf16h(v.w - bf16f(h3));
        int e = half*256 + lane*4;
        int boff = (e*2) ^ ((wv & 7) << 4);
        *(uint2*)&Xh[wv*512 + (boff >> 1)] = make_uint2(h0|(h1<<16), h2|(h3<<16));
        *(uint2*)&Xl[wv*512 + (boff >> 1)] = make_uint2(l0|(l1<<16), l2|(l3<<16));
    }
    __syncthreads();

    // ---- GEMM1: pure LDS + MFMA (weights already in regs) ----
    f32x4 acc = (f32x4){bb1, bb1, bb1, bb1};
    #pragma unroll
    for (int ks = 0; ks < KS1; ks++) {
        int ab = ((ks*64 + kg*16) ^ ((crow & 7) << 4)) >> 1;
        short8 xh = *(const short8*)&Xh[crow*512 + ab];
        short8 xl = *(const short8*)&Xl[crow*512 + ab];
        acc = __builtin_amdgcn_mfma_f32_16x16x32_bf16(xl, b1r[ks], acc, 0, 0, 0);
        acc = __builtin_amdgcn_mfma_f32_16x16x32_bf16(xh, b1r[ks], acc, 0, 0, 0);
    }
    // relu + split to bf16 hi/lo H (swizzled)
    #pragma unroll
    for (int reg = 0; reg < 4; reg++) {
        int row = kg*4 + reg;
        float h = fmaxf(acc[reg], 0.f);
        uint hh = bf16h(h);
        uint hl = bf16h(h - bf16f(hh));
        int boff = (col*2) ^ ((row & 7) << 4);
        Hh[row*256 + (boff >> 1)] = (ushort)hh;
        Hl[row*256 + (boff >> 1)] = (ushort)hl;
    }
    __syncthreads();

    // ---- GEMM2: pure LDS + MFMA ----
    f32x4 acc2 = (f32x4){bb2, bb2, bb2, bb2};
    #pragma unroll
    for (int ks = 0; ks < KS2; ks++) {
        int ab = ((ks*64 + kg*16) ^ ((crow & 7) << 4)) >> 1;
        short8 hh = *(const short8*)&Hh[crow*256 + ab];
        short8 hl = *(const short8*)&Hl[crow*256 + ab];
        acc2 = __builtin_amdgcn_mfma_f32_16x16x32_bf16(hl, b2r[ks], acc2, 0, 0, 0);
        acc2 = __builtin_amdgcn_mfma_f32_16x16x32_bf16(hh, b2r[ks], acc2, 0, 0, 0);
    }
    // ---- store y (f32) ----
    const int ob = NINIT + l*MM;
    #pragma unroll
    for (int reg = 0; reg < 4; reg++) {
        int row = kg*4 + reg;
        int idx = idx_s[row];
        if (idx >= 0) store[(size_t)(ob + idx)*D_ + col] = acc2[reg];
    }

    // ---- fused eval: val[row] = sum_col y*we  (16-lane shfl + cross-wave LDS) ----
    float pv[4];
    #pragma unroll
    for (int reg = 0; reg < 4; reg++) pv[reg] = acc2[reg] * we;
    #pragma unroll
    for (int off = 1; off < 16; off <<= 1) {
        #pragma unroll
        for (int reg = 0; reg < 4; reg++) pv[reg] += __shfl_xor(pv[reg], off);
    }
    if (crow == 0) {
        #pragma unroll
        for (int reg = 0; reg < 4; reg++) vred[kg*4 + reg][wv] = pv[reg];
    }
    __syncthreads();
    if (t < TB) {                                // wave 0, lanes 0..15: one row each
        float val = 0.f;
        #pragma unroll
        for (int w16 = 0; w16 < 16; w16++) val += vred[t][w16];
        int idx = idx_s[t];
        float A=0.f, B=0.f, pOK=0.f, nOK=0.f, tp=0.f, tn=0.f;
        if (idx >= 0) {
            int n = ob + idx;
            bce_terms(val + bev, (float)labeled[n], pos[n], neg[n],
                      &A, &B, &pOK, &nOK, &tp, &tn);
        }
        #pragma unroll
        for (int off = 1; off < 16; off <<= 1) {
            A   += __shfl_xor(A, off);   B  += __shfl_xor(B, off);
            pOK += __shfl_xor(pOK, off); nOK += __shfl_xor(nOK, off);
            tp  += __shfl_xor(tp, off);  tn += __shfl_xor(tn, off);
        }
        if (t == 0) {
            float* ps = &partials[((size_t)l*NB + blockIdx.x)*6];
            ps[0]=A; ps[1]=B; ps[2]=pOK; ps[3]=nOK; ps[4]=tp; ps[5]=tn;
        }
    }
}

// ---------------- final reduce + pw + loss ----------------
__global__ __launch_bounds__(256) void final_kernel(const float* __restrict__ partials,
                                                    float* __restrict__ out) {
    int t = threadIdx.x;
    float sA=0.f, sB=0.f, sP=0.f, sN=0.f, sTP=0.f, sTN=0.f;
    for (int g = t; g < NPART; g += 256) {
        sA  += partials[g*6+0]; sB  += partials[g*6+1]; sP  += partials[g*6+2];
        sN  += partials[g*6+3]; sTP += partials[g*6+4]; sTN += partials[g*6+5];
    }
    __shared__ float red[256];
    #define FRED(V) { __syncthreads(); red[t] = (V); __syncthreads();                     \
        for (int s_ = 128; s_ > 0; s_ >>= 1) { if (t < s_) red[t] += red[t+s_]; __syncthreads(); } \
        (V) = red[0]; __syncthreads(); }
    FRED(sA) FRED(sB) FRED(sP) FRED(sN) FRED(sTP) FRED(sTN)
    #undef FRED
    if (t == 0) {
        float pw = sTN / fmaxf(sTP, 1e-8f);
        out[0] = -(pw*sA + sB);
        out[1] = sP; out[2] = sN; out[3] = sTP; out[4] = sTN;
    }
}

extern "C" void kernel_launch(void* const* d_in, const int* in_sizes, int n_in,
                              void* d_out, int out_size, void* d_ws, size_t ws_size,
                              hipStream_t stream) {
    const float* pt        = (const float*)d_in[0];
    const float* init_tab  = (const float*)d_in[1];
    const float* sine_tab  = (const float*)d_in[2];
    const float* W1        = (const float*)d_in[3];
    const float* b1        = (const float*)d_in[4];
    const float* t1        = (const float*)d_in[5];
    const float* W2        = (const float*)d_in[6];
    const float* b2        = (const float*)d_in[7];
    const float* w_eval    = (const float*)d_in[8];
    const float* b_eval    = (const float*)d_in[9];
    const float* t_eval    = (const float*)d_in[10];
    const float* pos       = (const float*)d_in[11];
    const float* neg       = (const float*)d_in[12];
    const int*   init_thax = (const int*)d_in[13];
    const int*   init_sine = (const int*)d_in[14];
    const int*   drule     = (const int*)d_in[15];
    const int*   dparents  = (const int*)d_in[16];
    const int*   labeled   = (const int*)d_in[17];
    float* out = (float*)d_out;

    // workspace layout (bytes, all 16-aligned)
    char* w = (char*)d_ws;
    const size_t STORE_B = (size_t)NTOT * D_ * 4;            // 75,497,472
    const size_t SORT_B  = (size_t)LL * MP * 4;              //    270,336
    const size_t P1_B    = (size_t)R_*KS1*NT*64*8*2;         //  2,097,152
    const size_t P2_B    = (size_t)R_*KS2*NT*64*8*2;         //  1,048,576
    float*  store    = (float*) w;                    w += STORE_B;
    int*    sorted   = (int*)   w;                    w += SORT_B;
    ushort* P1h      = (ushort*)w;                    w += P1_B;
    ushort* P2h      = (ushort*)w;                    w += P2_B;
    float*  partials = (float*) w;                    // NPART*6*4 = 150,528

    prep_kernel<<<PREP_BLKS, 256, 0, stream>>>(drule, sorted, init_tab, sine_tab,
                                               init_thax, init_sine, store,
                                               W1, P1h, W2, P2h,
                                               w_eval, b_eval, t_eval, pt,
                                               pos, neg, labeled, partials);
    for (int l = 0; l < LL; l++)
        layer_kernel<<<NB, 1024, 0, stream>>>(store, sorted, drule, dparents,
                                              P1h, P2h, b1, t1, b2, pt,
                                              w_eval, b_eval, t_eval,
                                              pos, neg, labeled, partials, l);
    final_kernel<<<1, 256, 0, stream>>>(partials, out);
}

// Round 8
// 319.237 us; speedup vs baseline: 1.2912x; 1.2912x over previous
//
#include <hip/hip_runtime.h>
#include <math.h>

#define D_    256
#define H_    256
#define R_    8
#define NINIT 8192
#define LL    16
#define MM    4096
#define NTOT  (NINIT + LL*MM)   // 73728
#define TB    32                // nodes per MFMA tile/block (32x32 MFMA)
#define MP    (MM + R_*TB)      // 4352 padded slots per layer
#define NB    (MP/TB)           // 136 blocks per layer (~132 active < 256 CUs)
#define KS1   32                // K-steps GEMM1 (512/16)
#define KS2   16                // K-steps GEMM2 (256/16)
#define NT32  8                 // n-tiles (256/32)

#define EMB_BLKS (NINIT*64/256)          // 2048
#define PK1_BLKS (R_*KS1*NT32*64/256)    // 512
#define PK2_BLKS (R_*KS2*NT32*64/256)    // 256
#define PREP_BLKS (LL + EMB_BLKS + PK1_BLKS + PK2_BLKS)
#define NPART (LL*NB + EMB_BLKS)         // 4224 partial slots (6 floats each)

typedef __attribute__((ext_vector_type(8))) short short8;
typedef __attribute__((ext_vector_type(16))) float f32x16;

__device__ __forceinline__ uint bf16h(float f) {           // f32 -> bf16 bits (RNE)
    uint u = __float_as_uint(f);
    return (u + 0x7fffu + ((u >> 16) & 1u)) >> 16;
}
__device__ __forceinline__ float bf16f(uint h) { return __uint_as_float(h << 16); }

// BCE partial terms for one node, given val (pre-sigmoid logit)
__device__ __forceinline__ void bce_terms(float val, float lab, float p, float ng,
                                          float* A, float* B, float* pOK, float* nOK,
                                          float* tp, float* tn) {
    float tot = p + ng;
    float target = p / fmaxf(tot, 1e-8f);
    float ls  = (val >= 0.f) ? -log1pf(expf(-val)) : (val  - log1pf(expf( val)));
    float lns = (val <= 0.f) ? -log1pf(expf( val)) : (-val - log1pf(expf(-val)));
    *A = lab*tot*target*ls;
    *B = lab*tot*(1.f - target)*lns;
    *pOK = (val >= 0.f) ? lab*p : 0.f;
    *nOK = (val <  0.f) ? lab*ng : 0.f;
    *tp = p*lab; *tn = ng*lab;
}

// ---------------- prep bodies ----------------
__device__ void sort_body(int l, int t, const int* __restrict__ rule,
                          int* __restrict__ sorted) {
    __shared__ int hist[R_], cursor[R_];
    if (t < R_) hist[t] = 0;
    __syncthreads();
    for (int m = t; m < MM; m += 256) atomicAdd(&hist[rule[l*MM + m]], 1);
    __syncthreads();
    if (t == 0) {
        int off = 0;
        for (int r = 0; r < R_; r++) { cursor[r] = off; off += ((hist[r] + TB - 1)/TB)*TB; }
    }
    for (int m = t; m < MP; m += 256) sorted[l*MP + m] = -1;
    __syncthreads();
    for (int m = t; m < MM; m += 256) {
        int r = rule[l*MM + m];
        int pos = atomicAdd(&cursor[r], 1);
        sorted[l*MP + pos] = m;
    }
}

// embed + fused eval for init nodes (one wave = one node; block = 4 nodes)
__device__ void embed_body(int b, int t, const float* __restrict__ itab,
                           const float* __restrict__ stab,
                           const int* __restrict__ thax, const int* __restrict__ sine,
                           float* __restrict__ store,
                           const float* __restrict__ w_eval, const float* __restrict__ b_eval,
                           const float* __restrict__ t_eval, const float* __restrict__ pt,
                           const float* __restrict__ pos, const float* __restrict__ neg,
                           const int* __restrict__ labeled, float* __restrict__ partials) {
    __shared__ float ered[4][6];
    int gid = b*256 + t;
    int n = gid >> 6, d = (gid & 63) << 2;
    int th = thax[n], si = sine[n];
    const float4 a = *(const float4*)&itab[th*D_ + d];
    const float4 bb = *(const float4*)&stab[si*D_ + d];
    float4 o; o.x = a.x+bb.x; o.y = a.y+bb.y; o.z = a.z+bb.z; o.w = a.w+bb.w;
    *(float4*)&store[(size_t)n*D_ + d] = o;
    const float4 we = *(const float4*)&w_eval[d];
    float pv = o.x*we.x + o.y*we.y + o.z*we.z + o.w*we.w;
    #pragma unroll
    for (int off = 32; off > 0; off >>= 1) pv += __shfl_xor(pv, off);
    int wvid = t >> 6;
    if ((t & 63) == 0) {
        float val = pv + b_eval[0] + pt[0]*t_eval[0];
        float A, B, pOK, nOK, tp, tn;
        bce_terms(val, (float)labeled[n], pos[n], neg[n], &A, &B, &pOK, &nOK, &tp, &tn);
        ered[wvid][0]=A; ered[wvid][1]=B; ered[wvid][2]=pOK;
        ered[wvid][3]=nOK; ered[wvid][4]=tp; ered[wvid][5]=tn;
    }
    __syncthreads();
    if (t < 6) partials[((size_t)LL*NB + b)*6 + t] =
        ered[0][t] + ered[1][t] + ered[2][t] + ered[3][t];
}

// 32x32x16 fragment pack:
// Ph[((r*KSn + ks)*NT32 + nt)*64 + lane][j] = bf16(W[r][ks*16 + (lane>>5)*8 + j][nt*32 + (lane&31)])
__device__ void pack_body(int gid, const float* __restrict__ W,
                          ushort* __restrict__ Ph, int KSn) {
    int lane = gid & 63;
    int nt   = (gid >> 6) & 7;
    int ks   = (gid >> 9) % KSn;
    int r    = gid / (512*KSn);
    int K = KSn*16;
    int k0 = ks*16 + (lane >> 5)*8;
    int c  = nt*32 + (lane & 31);
    const float* src = W + ((size_t)r*K + k0)*256 + c;
    uint h[8];
    #pragma unroll
    for (int j = 0; j < 8; j++) h[j] = bf16h(src[(size_t)j*256]);
    size_t o = (size_t)gid*8;
    *(uint4*)&Ph[o] = make_uint4(h[0]|(h[1]<<16), h[2]|(h[3]<<16), h[4]|(h[5]<<16), h[6]|(h[7]<<16));
}

__global__ __launch_bounds__(256) void prep_kernel(
        const int* __restrict__ drule, int* __restrict__ sorted,
        const float* __restrict__ itab, const float* __restrict__ stab,
        const int* __restrict__ thax, const int* __restrict__ sine,
        float* __restrict__ store,
        const float* __restrict__ W1, ushort* __restrict__ P1h,
        const float* __restrict__ W2, ushort* __restrict__ P2h,
        const float* __restrict__ w_eval, const float* __restrict__ b_eval,
        const float* __restrict__ t_eval, const float* __restrict__ pt,
        const float* __restrict__ pos, const float* __restrict__ neg,
        const int* __restrict__ labeled, float* __restrict__ partials) {
    int b = blockIdx.x, t = threadIdx.x;
    if (b < LL) {
        sort_body(b, t, drule, sorted);
    } else if (b < LL + EMB_BLKS) {
        embed_body(b - LL, t, itab, stab, thax, sine, store,
                   w_eval, b_eval, t_eval, pt, pos, neg, labeled, partials);
    } else if (b < LL + EMB_BLKS + PK1_BLKS) {
        pack_body((b - LL - EMB_BLKS)*256 + t, W1, P1h, KS1);
    } else {
        pack_body((b - LL - EMB_BLKS - PK1_BLKS)*256 + t, W2, P2h, KS2);
    }
}

// ---------------- one DAG layer + fused eval ----------------
// 32-node tile, 8 waves, 1 n-tile (32 cols) per wave, mfma_f32_32x32x16_bf16.
// Weights hi-only bf16; activations split-bf16 (hi+lo). ~132 active blocks < 256 CUs.
__global__ __launch_bounds__(512) void layer_kernel(float* __restrict__ store,
        const int* __restrict__ sorted, const int* __restrict__ rule,
        const int* __restrict__ parents,
        const ushort* __restrict__ P1h, const ushort* __restrict__ P2h,
        const float* __restrict__ b1, const float* __restrict__ t1,
        const float* __restrict__ b2, const float* __restrict__ pt,
        const float* __restrict__ w_eval, const float* __restrict__ b_eval,
        const float* __restrict__ t_eval,
        const float* __restrict__ pos, const float* __restrict__ neg,
        const int* __restrict__ labeled, float* __restrict__ partials, int l) {
    __shared__ ushort Xh[TB*512], Xl[TB*512];   // 32 rows x 512 bf16 hi/lo, swizzled (64 KB)
    __shared__ ushort Hh[TB*256], Hl[TB*256];   // 32 rows x 256 bf16 hi/lo (32 KB)
    __shared__ int idx_s[TB];
    __shared__ float vred[TB][NT32 + 1];
    const int t = threadIdx.x, lane = t & 63, wv = t >> 6;   // wv = 0..7
    const int base = l*MP + blockIdx.x*TB;
    const int idx0 = sorted[base];
    if (idx0 < 0) {                              // fully-padded tail tile
        if (t < 6) partials[((size_t)l*NB + blockIdx.x)*6 + t] = 0.f;
        return;
    }
    const int r = rule[l*MM + idx0];
    const int arow = lane & 31, hk = lane >> 5;  // A row / k-group
    const int col = wv*32 + arow;
    const float tw = pt[1];
    const float bev = b_eval[0] + pt[0]*t_eval[0];
    const float bb1 = b1[r*H_ + col] + tw * t1[r*H_ + col];
    const float bb2 = b2[r*D_ + col];
    const float we  = w_eval[col];

    // ---- gather: wave wv stages rows wv*4..wv*4+3 (2 parent halves, float4/lane) ----
    #pragma unroll
    for (int rr = 0; rr < 4; rr++) {
        int row = wv*4 + rr;
        int idxr = sorted[base + row];
        if (lane == 0) idx_s[row] = idxr;
        #pragma unroll
        for (int half = 0; half < 2; half++) {
            float4 v = make_float4(0.f, 0.f, 0.f, 0.f);
            if (idxr >= 0) {
                int p = parents[(l*MM + idxr)*2 + half];
                v = *(const float4*)&store[(size_t)p*D_ + lane*4];
            }
            uint h0 = bf16h(v.x), h1 = bf16h(v.y), h2 = bf16h(v.z), h3 = bf16h(v.w);
            uint l0 = bf16h(v.x - bf16f(h0)), l1 = bf16h(v.y - bf16f(h1));
            uint l2 = bf16h(v.z - bf16f(h2)), l3 = bf16h(v.w - bf16f(h3));
            int e = half*256 + lane*4;
            int boff = (e*2) ^ ((row & 31) << 4);     // 5-bit XOR swizzle in 1024B row
            *(uint2*)&Xh[row*512 + (boff >> 1)] = make_uint2(h0|(h1<<16), h2|(h3<<16));
            *(uint2*)&Xl[row*512 + (boff >> 1)] = make_uint2(l0|(l1<<16), l2|(l3<<16));
        }
    }
    __syncthreads();

    // ---- GEMM1: [32x512] @ W1h[512x256], 2 MFMA/kstep (xl,xh); wave owns 32-col tile ----
    f32x16 acc;
    #pragma unroll
    for (int q = 0; q < 16; q++) acc[q] = bb1;
    const short8* B1hp = (const short8*)P1h + ((size_t)r*KS1*NT32 + wv)*64 + lane;
    const int xsw = (arow & 31) << 4;
    #pragma unroll
    for (int ks = 0; ks < KS1; ks++) {
        int ab = ((ks*32 + hk*16) ^ xsw) >> 1;
        short8 xh = *(const short8*)&Xh[arow*512 + ab];
        short8 xl = *(const short8*)&Xl[arow*512 + ab];
        short8 bh = B1hp[(size_t)ks*NT32*64];
        acc = __builtin_amdgcn_mfma_f32_32x32x16_bf16(xl, bh, acc, 0, 0, 0);
        acc = __builtin_amdgcn_mfma_f32_32x32x16_bf16(xh, bh, acc, 0, 0, 0);
    }
    // relu + split to bf16 hi/lo H (swizzled). C row = (reg&3)+8*(reg>>2)+4*hk
    #pragma unroll
    for (int reg = 0; reg < 16; reg++) {
        int row = (reg & 3) + 8*(reg >> 2) + 4*hk;
        float h = fmaxf(acc[reg], 0.f);
        uint hh = bf16h(h);
        uint hl = bf16h(h - bf16f(hh));
        int boff = (col*2) ^ ((row & 31) << 4);       // within 512B row
        Hh[row*256 + (boff >> 1)] = (ushort)hh;
        Hl[row*256 + (boff >> 1)] = (ushort)hl;
    }
    __syncthreads();

    // ---- GEMM2: [32x256] @ W2h[256x256] ----
    f32x16 acc2;
    #pragma unroll
    for (int q = 0; q < 16; q++) acc2[q] = bb2;
    const short8* B2hp = (const short8*)P2h + ((size_t)r*KS2*NT32 + wv)*64 + lane;
    #pragma unroll
    for (int ks = 0; ks < KS2; ks++) {
        int ab = ((ks*32 + hk*16) ^ xsw) >> 1;
        short8 hh = *(const short8*)&Hh[arow*256 + ab];
        short8 hl = *(const short8*)&Hl[arow*256 + ab];
        short8 bh = B2hp[(size_t)ks*NT32*64];
        acc2 = __builtin_amdgcn_mfma_f32_32x32x16_bf16(hl, bh, acc2, 0, 0, 0);
        acc2 = __builtin_amdgcn_mfma_f32_32x32x16_bf16(hh, bh, acc2, 0, 0, 0);
    }
    // ---- store y (f32) ----
    const int ob = NINIT + l*MM;
    #pragma unroll
    for (int reg = 0; reg < 16; reg++) {
        int row = (reg & 3) + 8*(reg >> 2) + 4*hk;
        int idx = idx_s[row];
        if (idx >= 0) store[(size_t)(ob + idx)*D_ + col] = acc2[reg];
    }

    // ---- fused eval: val[row] = sum_col y*we ----
    float pv[16];
    #pragma unroll
    for (int reg = 0; reg < 16; reg++) pv[reg] = acc2[reg] * we;
    #pragma unroll
    for (int off = 1; off < 32; off <<= 1) {
        #pragma unroll
        for (int reg = 0; reg < 16; reg++) pv[reg] += __shfl_xor(pv[reg], off);
    }
    if (arow == 0) {
        #pragma unroll
        for (int reg = 0; reg < 16; reg++)
            vred[(reg & 3) + 8*(reg >> 2) + 4*hk][wv] = pv[reg];
    }
    __syncthreads();
    if (t < TB) {                                // lanes 0..31 of wave 0: one row each
        float val = 0.f;
        #pragma unroll
        for (int w8 = 0; w8 < NT32; w8++) val += vred[t][w8];
        int idx = idx_s[t];
        float A=0.f, B=0.f, pOK=0.f, nOK=0.f, tp=0.f, tn=0.f;
        if (idx >= 0) {
            int n = ob + idx;
            bce_terms(val + bev, (float)labeled[n], pos[n], neg[n],
                      &A, &B, &pOK, &nOK, &tp, &tn);
        }
        #pragma unroll
        for (int off = 1; off < 32; off <<= 1) {
            A   += __shfl_xor(A, off);   B  += __shfl_xor(B, off);
            pOK += __shfl_xor(pOK, off); nOK += __shfl_xor(nOK, off);
            tp  += __shfl_xor(tp, off);  tn += __shfl_xor(tn, off);
        }
        if (t == 0) {
            float* ps = &partials[((size_t)l*NB + blockIdx.x)*6];
            ps[0]=A; ps[1]=B; ps[2]=pOK; ps[3]=nOK; ps[4]=tp; ps[5]=tn;
        }
    }
}

// ---------------- final reduce + pw + loss ----------------
__global__ __launch_bounds__(256) void final_kernel(const float* __restrict__ partials,
                                                    float* __restrict__ out) {
    int t = threadIdx.x;
    float sA=0.f, sB=0.f, sP=0.f, sN=0.f, sTP=0.f, sTN=0.f;
    for (int g = t; g < NPART; g += 256) {
        sA  += partials[g*6+0]; sB  += partials[g*6+1]; sP  += partials[g*6+2];
        sN  += partials[g*6+3]; sTP += partials[g*6+4]; sTN += partials[g*6+5];
    }
    __shared__ float red[256];
    #define FRED(V) { __syncthreads(); red[t] = (V); __syncthreads();                     \
        for (int s_ = 128; s_ > 0; s_ >>= 1) { if (t < s_) red[t] += red[t+s_]; __syncthreads(); } \
        (V) = red[0]; __syncthreads(); }
    FRED(sA) FRED(sB) FRED(sP) FRED(sN) FRED(sTP) FRED(sTN)
    #undef FRED
    if (t == 0) {
        float pw = sTN / fmaxf(sTP, 1e-8f);
        out[0] = -(pw*sA + sB);
        out[1] = sP; out[2] = sN; out[3] = sTP; out[4] = sTN;
    }
}

extern "C" void kernel_launch(void* const* d_in, const int* in_sizes, int n_in,
                              void* d_out, int out_size, void* d_ws, size_t ws_size,
                              hipStream_t stream) {
    const float* pt        = (const float*)d_in[0];
    const float* init_tab  = (const float*)d_in[1];
    const float* sine_tab  = (const float*)d_in[2];
    const float* W1        = (const float*)d_in[3];
    const float* b1        = (const float*)d_in[4];
    const float* t1        = (const float*)d_in[5];
    const float* W2        = (const float*)d_in[6];
    const float* b2        = (const float*)d_in[7];
    const float* w_eval    = (const float*)d_in[8];
    const float* b_eval    = (const float*)d_in[9];
    const float* t_eval    = (const float*)d_in[10];
    const float* pos       = (const float*)d_in[11];
    const float* neg       = (const float*)d_in[12];
    const int*   init_thax = (const int*)d_in[13];
    const int*   init_sine = (const int*)d_in[14];
    const int*   drule     = (const int*)d_in[15];
    const int*   dparents  = (const int*)d_in[16];
    const int*   labeled   = (const int*)d_in[17];
    float* out = (float*)d_out;

    // workspace layout (bytes, all 16-aligned)
    char* w = (char*)d_ws;
    const size_t STORE_B = (size_t)NTOT * D_ * 4;            // 75,497,472
    const size_t SORT_B  = (size_t)LL * MP * 4;              //    278,528
    const size_t P1_B    = (size_t)R_*KS1*NT32*64*8*2;       //  2,097,152
    const size_t P2_B    = (size_t)R_*KS2*NT32*64*8*2;       //  1,048,576
    float*  store    = (float*) w;                    w += STORE_B;
    int*    sorted   = (int*)   w;                    w += SORT_B;
    ushort* P1h      = (ushort*)w;                    w += P1_B;
    ushort* P2h      = (ushort*)w;                    w += P2_B;
    float*  partials = (float*) w;                    // NPART*6*4 = 101,376

    prep_kernel<<<PREP_BLKS, 256, 0, stream>>>(drule, sorted, init_tab, sine_tab,
                                               init_thax, init_sine, store,
                                               W1, P1h, W2, P2h,
                                               w_eval, b_eval, t_eval, pt,
                                               pos, neg, labeled, partials);
    for (int l = 0; l < LL; l++)
        layer_kernel<<<NB, 512, 0, stream>>>(store, sorted, drule, dparents,
                                             P1h, P2h, b1, t1, b2, pt,
                                             w_eval, b_eval, t_eval,
                                             pos, neg, labeled, partials, l);
    final_kernel<<<1, 256, 0, stream>>>(partials, out);
}

// Round 9
// 301.200 us; speedup vs baseline: 1.3685x; 1.0599x over previous
//
#include <hip/hip_runtime.h>
#include <math.h>

#define D_    256
#define H_    256
#define R_    8
#define NINIT 8192
#define LL    16
#define MM    4096
#define NTOT  (NINIT + LL*MM)   // 73728
#define TB    32                // nodes per block (two 16-row MFMA subtiles)
#define MP    (MM + R_*TB)      // 4352 padded slots per layer
#define NB    (MP/TB)           // 136 blocks per layer (<= 256 CUs, no straggle)
#define KS1   16                // K-steps GEMM1 (512/32)
#define KS2   8                 // K-steps GEMM2 (256/32)
#define NT    16                // n-tiles (256/16)

#define EMB_BLKS (NINIT*64/256)        // 2048
#define PK1_BLKS (R_*KS1*NT*64/256)    // 512
#define PK2_BLKS (R_*KS2*NT*64/256)    // 256
#define PREP_BLKS (LL + EMB_BLKS + PK1_BLKS + PK2_BLKS)
#define NPART (LL*NB + EMB_BLKS)       // 4224 partial slots (6 floats each)

typedef __attribute__((ext_vector_type(8))) short short8;
typedef __attribute__((ext_vector_type(4))) float f32x4;

__device__ __forceinline__ uint bf16h(float f) {           // f32 -> bf16 bits (RNE)
    uint u = __float_as_uint(f);
    return (u + 0x7fffu + ((u >> 16) & 1u)) >> 16;
}
__device__ __forceinline__ float bf16f(uint h) { return __uint_as_float(h << 16); }

// BCE partial terms for one node, given val (pre-sigmoid logit)
__device__ __forceinline__ void bce_terms(float val, float lab, float p, float ng,
                                          float* A, float* B, float* pOK, float* nOK,
                                          float* tp, float* tn) {
    float tot = p + ng;
    float target = p / fmaxf(tot, 1e-8f);
    float ls  = (val >= 0.f) ? -log1pf(expf(-val)) : (val  - log1pf(expf( val)));
    float lns = (val <= 0.f) ? -log1pf(expf( val)) : (-val - log1pf(expf(-val)));
    *A = lab*tot*target*ls;
    *B = lab*tot*(1.f - target)*lns;
    *pOK = (val >= 0.f) ? lab*p : 0.f;
    *nOK = (val <  0.f) ? lab*ng : 0.f;
    *tp = p*lab; *tn = ng*lab;
}

// ---------------- prep bodies ----------------
__device__ void sort_body(int l, int t, const int* __restrict__ rule,
                          int* __restrict__ sorted) {
    __shared__ int hist[R_], cursor[R_];
    if (t < R_) hist[t] = 0;
    __syncthreads();
    for (int m = t; m < MM; m += 256) atomicAdd(&hist[rule[l*MM + m]], 1);
    __syncthreads();
    if (t == 0) {
        int off = 0;
        for (int r = 0; r < R_; r++) { cursor[r] = off; off += ((hist[r] + TB - 1)/TB)*TB; }
    }
    for (int m = t; m < MP; m += 256) sorted[l*MP + m] = -1;
    __syncthreads();
    for (int m = t; m < MM; m += 256) {
        int r = rule[l*MM + m];
        int pos = atomicAdd(&cursor[r], 1);
        sorted[l*MP + pos] = m;
    }
}

// embed + fused eval for init nodes (one wave = one node; block = 4 nodes)
__device__ void embed_body(int b, int t, const float* __restrict__ itab,
                           const float* __restrict__ stab,
                           const int* __restrict__ thax, const int* __restrict__ sine,
                           float* __restrict__ store,
                           const float* __restrict__ w_eval, const float* __restrict__ b_eval,
                           const float* __restrict__ t_eval, const float* __restrict__ pt,
                           const float* __restrict__ pos, const float* __restrict__ neg,
                           const int* __restrict__ labeled, float* __restrict__ partials) {
    __shared__ float ered[4][6];
    int gid = b*256 + t;
    int n = gid >> 6, d = (gid & 63) << 2;
    int th = thax[n], si = sine[n];
    const float4 a = *(const float4*)&itab[th*D_ + d];
    const float4 bb = *(const float4*)&stab[si*D_ + d];
    float4 o; o.x = a.x+bb.x; o.y = a.y+bb.y; o.z = a.z+bb.z; o.w = a.w+bb.w;
    *(float4*)&store[(size_t)n*D_ + d] = o;
    const float4 we = *(const float4*)&w_eval[d];
    float pv = o.x*we.x + o.y*we.y + o.z*we.z + o.w*we.w;
    #pragma unroll
    for (int off = 32; off > 0; off >>= 1) pv += __shfl_xor(pv, off);
    int wvid = t >> 6;
    if ((t & 63) == 0) {
        float val = pv + b_eval[0] + pt[0]*t_eval[0];
        float A, B, pOK, nOK, tp, tn;
        bce_terms(val, (float)labeled[n], pos[n], neg[n], &A, &B, &pOK, &nOK, &tp, &tn);
        ered[wvid][0]=A; ered[wvid][1]=B; ered[wvid][2]=pOK;
        ered[wvid][3]=nOK; ered[wvid][4]=tp; ered[wvid][5]=tn;
    }
    __syncthreads();
    if (t < 6) partials[((size_t)LL*NB + b)*6 + t] =
        ered[0][t] + ered[1][t] + ered[2][t] + ered[3][t];
}

// 16x16x32 fragment pack:
// Ph[((r*KSn + ks)*NT + nt)*64 + lane][j] = bf16(W[r][ks*32 + (lane>>4)*8 + j][nt*16 + (lane&15)])
__device__ void pack_body(int gid, const float* __restrict__ W,
                          ushort* __restrict__ Ph, int KSn) {
    int lane = gid & 63;
    int nt   = (gid >> 6) & 15;
    int ks   = (gid >> 10) % KSn;
    int r    = gid / (1024*KSn);
    int K = KSn*32;
    int k0 = ks*32 + (lane >> 4)*8;
    int c  = nt*16 + (lane & 15);
    const float* src = W + ((size_t)r*K + k0)*256 + c;
    uint h[8];
    #pragma unroll
    for (int j = 0; j < 8; j++) h[j] = bf16h(src[(size_t)j*256]);
    size_t o = (size_t)gid*8;
    *(uint4*)&Ph[o] = make_uint4(h[0]|(h[1]<<16), h[2]|(h[3]<<16), h[4]|(h[5]<<16), h[6]|(h[7]<<16));
}

__global__ __launch_bounds__(256) void prep_kernel(
        const int* __restrict__ drule, int* __restrict__ sorted,
        const float* __restrict__ itab, const float* __restrict__ stab,
        const int* __restrict__ thax, const int* __restrict__ sine,
        float* __restrict__ store,
        const float* __restrict__ W1, ushort* __restrict__ P1h,
        const float* __restrict__ W2, ushort* __restrict__ P2h,
        const float* __restrict__ w_eval, const float* __restrict__ b_eval,
        const float* __restrict__ t_eval, const float* __restrict__ pt,
        const float* __restrict__ pos, const float* __restrict__ neg,
        const int* __restrict__ labeled, float* __restrict__ partials) {
    int b = blockIdx.x, t = threadIdx.x;
    if (b < LL) {
        sort_body(b, t, drule, sorted);
    } else if (b < LL + EMB_BLKS) {
        embed_body(b - LL, t, itab, stab, thax, sine, store,
                   w_eval, b_eval, t_eval, pt, pos, neg, labeled, partials);
    } else if (b < LL + EMB_BLKS + PK1_BLKS) {
        pack_body((b - LL - EMB_BLKS)*256 + t, W1, P1h, KS1);
    } else {
        pack_body((b - LL - EMB_BLKS - PK1_BLKS)*256 + t, W2, P2h, KS2);
    }
}

// ---------------- one DAG layer + fused eval ----------------
// 32-node tile, 16 waves (4/SIMD), 16x16x32 MFMA; wave owns one 16-col n-tile
// for TWO row-subtiles (rows crow, crow+16). Weights hi-only; activations split-bf16.
__global__ __launch_bounds__(1024) void layer_kernel(float* __restrict__ store,
        const int* __restrict__ sorted, const int* __restrict__ rule,
        const int* __restrict__ parents,
        const ushort* __restrict__ P1h, const ushort* __restrict__ P2h,
        const float* __restrict__ b1, const float* __restrict__ t1,
        const float* __restrict__ b2, const float* __restrict__ pt,
        const float* __restrict__ w_eval, const float* __restrict__ b_eval,
        const float* __restrict__ t_eval,
        const float* __restrict__ pos, const float* __restrict__ neg,
        const int* __restrict__ labeled, float* __restrict__ partials, int l) {
    __shared__ ushort Xh[TB*512], Xl[TB*512];   // 32 rows x 512 bf16 hi/lo, swizzled (64 KB)
    __shared__ ushort Hh[TB*256], Hl[TB*256];   // 32 rows x 256 bf16 hi/lo (32 KB)
    __shared__ int idx_s[TB];
    __shared__ float vred[TB][17];
    const int t = threadIdx.x, lane = t & 63, wv = t >> 6;   // wv = 0..15
    const int base = l*MP + blockIdx.x*TB;
    const int idx0 = sorted[base];
    if (idx0 < 0) {                              // fully-padded tail tile
        if (t < 6) partials[((size_t)l*NB + blockIdx.x)*6 + t] = 0.f;
        return;
    }
    const int r = rule[l*MM + idx0];
    const int crow = lane & 15, kg = lane >> 4;
    const int col = wv*16 + crow;
    const float tw = pt[1];
    const float bev = b_eval[0] + pt[0]*t_eval[0];
    const float bb1 = b1[r*H_ + col] + tw * t1[r*H_ + col];
    const float bb2 = b2[r*D_ + col];
    const float we  = w_eval[col];

    // ---- gather: wave wv stages rows {wv, wv+16} (2 parent halves, float4/lane) ----
    #pragma unroll
    for (int rr = 0; rr < 2; rr++) {
        int row = wv + rr*16;
        int idxr = sorted[base + row];
        if (lane == 0) idx_s[row] = idxr;
        #pragma unroll
        for (int half = 0; half < 2; half++) {
            float4 v = make_float4(0.f, 0.f, 0.f, 0.f);
            if (idxr >= 0) {
                int p = parents[(l*MM + idxr)*2 + half];
                v = *(const float4*)&store[(size_t)p*D_ + lane*4];
            }
            uint h0 = bf16h(v.x), h1 = bf16h(v.y), h2 = bf16h(v.z), h3 = bf16h(v.w);
            uint l0 = bf16h(v.x - bf16f(h0)), l1 = bf16h(v.y - bf16f(h1));
            uint l2 = bf16h(v.z - bf16f(h2)), l3 = bf16h(v.w - bf16f(h3));
            int e = half*256 + lane*4;
            int boff = (e*2) ^ ((row & 7) << 4);
            *(uint2*)&Xh[row*512 + (boff >> 1)] = make_uint2(h0|(h1<<16), h2|(h3<<16));
            *(uint2*)&Xl[row*512 + (boff >> 1)] = make_uint2(l0|(l1<<16), l2|(l3<<16));
        }
    }
    __syncthreads();

    // ---- GEMM1: [32x512] @ W1h[512x256]; 1 B-load serves both row subtiles ----
    f32x4 acc0 = (f32x4){bb1, bb1, bb1, bb1};
    f32x4 acc1 = (f32x4){bb1, bb1, bb1, bb1};
    const short8* B1hp = (const short8*)P1h + ((size_t)r*KS1*NT + wv)*64 + lane;
    #pragma unroll
    for (int ks = 0; ks < KS1; ks++) {
        int ab = ((ks*64 + kg*16) ^ ((crow & 7) << 4)) >> 1;   // (crow+16)&7 == crow&7
        short8 xh0 = *(const short8*)&Xh[crow*512 + ab];
        short8 xl0 = *(const short8*)&Xl[crow*512 + ab];
        short8 xh1 = *(const short8*)&Xh[(crow + 16)*512 + ab];
        short8 xl1 = *(const short8*)&Xl[(crow + 16)*512 + ab];
        short8 bh = B1hp[(size_t)ks*NT*64];
        acc0 = __builtin_amdgcn_mfma_f32_16x16x32_bf16(xl0, bh, acc0, 0, 0, 0);
        acc0 = __builtin_amdgcn_mfma_f32_16x16x32_bf16(xh0, bh, acc0, 0, 0, 0);
        acc1 = __builtin_amdgcn_mfma_f32_16x16x32_bf16(xl1, bh, acc1, 0, 0, 0);
        acc1 = __builtin_amdgcn_mfma_f32_16x16x32_bf16(xh1, bh, acc1, 0, 0, 0);
    }
    // relu + split to bf16 hi/lo H (swizzled); subtile row offsets 0 and 16
    #pragma unroll
    for (int reg = 0; reg < 4; reg++) {
        int row = kg*4 + reg;
        float h0 = fmaxf(acc0[reg], 0.f);
        float h1 = fmaxf(acc1[reg], 0.f);
        uint h0h = bf16h(h0), h1h = bf16h(h1);
        uint h0l = bf16h(h0 - bf16f(h0h)), h1l = bf16h(h1 - bf16f(h1h));
        int boff = (col*2) ^ ((row & 7) << 4);
        Hh[row*256 + (boff >> 1)] = (ushort)h0h;
        Hl[row*256 + (boff >> 1)] = (ushort)h0l;
        Hh[(row + 16)*256 + (boff >> 1)] = (ushort)h1h;
        Hl[(row + 16)*256 + (boff >> 1)] = (ushort)h1l;
    }
    __syncthreads();

    // ---- GEMM2: [32x256] @ W2h[256x256] ----
    f32x4 acc2 = (f32x4){bb2, bb2, bb2, bb2};
    f32x4 acc3 = (f32x4){bb2, bb2, bb2, bb2};
    const short8* B2hp = (const short8*)P2h + ((size_t)r*KS2*NT + wv)*64 + lane;
    #pragma unroll
    for (int ks = 0; ks < KS2; ks++) {
        int ab = ((ks*64 + kg*16) ^ ((crow & 7) << 4)) >> 1;
        short8 hh0 = *(const short8*)&Hh[crow*256 + ab];
        short8 hl0 = *(const short8*)&Hl[crow*256 + ab];
        short8 hh1 = *(const short8*)&Hh[(crow + 16)*256 + ab];
        short8 hl1 = *(const short8*)&Hl[(crow + 16)*256 + ab];
        short8 bh = B2hp[(size_t)ks*NT*64];
        acc2 = __builtin_amdgcn_mfma_f32_16x16x32_bf16(hl0, bh, acc2, 0, 0, 0);
        acc2 = __builtin_amdgcn_mfma_f32_16x16x32_bf16(hh0, bh, acc2, 0, 0, 0);
        acc3 = __builtin_amdgcn_mfma_f32_16x16x32_bf16(hl1, bh, acc3, 0, 0, 0);
        acc3 = __builtin_amdgcn_mfma_f32_16x16x32_bf16(hh1, bh, acc3, 0, 0, 0);
    }
    // ---- store y (f32), both subtiles ----
    const int ob = NINIT + l*MM;
    #pragma unroll
    for (int reg = 0; reg < 4; reg++) {
        int row = kg*4 + reg;
        int idxa = idx_s[row], idxb = idx_s[row + 16];
        if (idxa >= 0) store[(size_t)(ob + idxa)*D_ + col] = acc2[reg];
        if (idxb >= 0) store[(size_t)(ob + idxb)*D_ + col] = acc3[reg];
    }

    // ---- fused eval: val[row] = sum_col y*we (16-lane shfl + cross-wave LDS) ----
    float pv0[4], pv1[4];
    #pragma unroll
    for (int reg = 0; reg < 4; reg++) { pv0[reg] = acc2[reg]*we; pv1[reg] = acc3[reg]*we; }
    #pragma unroll
    for (int off = 1; off < 16; off <<= 1) {
        #pragma unroll
        for (int reg = 0; reg < 4; reg++) {
            pv0[reg] += __shfl_xor(pv0[reg], off);
            pv1[reg] += __shfl_xor(pv1[reg], off);
        }
    }
    if (crow == 0) {
        #pragma unroll
        for (int reg = 0; reg < 4; reg++) {
            vred[kg*4 + reg][wv]      = pv0[reg];
            vred[kg*4 + reg + 16][wv] = pv1[reg];
        }
    }
    __syncthreads();
    if (t < TB) {                                // lanes 0..31 of wave 0: one row each
        float val = 0.f;
        #pragma unroll
        for (int w16 = 0; w16 < 16; w16++) val += vred[t][w16];
        int idx = idx_s[t];
        float A=0.f, B=0.f, pOK=0.f, nOK=0.f, tp=0.f, tn=0.f;
        if (idx >= 0) {
            int n = ob + idx;
            bce_terms(val + bev, (float)labeled[n], pos[n], neg[n],
                      &A, &B, &pOK, &nOK, &tp, &tn);
        }
        #pragma unroll
        for (int off = 1; off < 32; off <<= 1) {
            A   += __shfl_xor(A, off);   B  += __shfl_xor(B, off);
            pOK += __shfl_xor(pOK, off); nOK += __shfl_xor(nOK, off);
            tp  += __shfl_xor(tp, off);  tn += __shfl_xor(tn, off);
        }
        if (t == 0) {
            float* ps = &partials[((size_t)l*NB + blockIdx.x)*6];
            ps[0]=A; ps[1]=B; ps[2]=pOK; ps[3]=nOK; ps[4]=tp; ps[5]=tn;
        }
    }
}

// ---------------- final reduce + pw + loss ----------------
__global__ __launch_bounds__(256) void final_kernel(const float* __restrict__ partials,
                                                    float* __restrict__ out) {
    int t = threadIdx.x;
    float sA=0.f, sB=0.f, sP=0.f, sN=0.f, sTP=0.f, sTN=0.f;
    for (int g = t; g < NPART; g += 256) {
        sA  += partials[g*6+0]; sB  += partials[g*6+1]; sP  += partials[g*6+2];
        sN  += partials[g*6+3]; sTP += partials[g*6+4]; sTN += partials[g*6+5];
    }
    __shared__ float red[256];
    #define FRED(V) { __syncthreads(); red[t] = (V); __syncthreads();                     \
        for (int s_ = 128; s_ > 0; s_ >>= 1) { if (t < s_) red[t] += red[t+s_]; __syncthreads(); } \
        (V) = red[0]; __syncthreads(); }
    FRED(sA) FRED(sB) FRED(sP) FRED(sN) FRED(sTP) FRED(sTN)
    #undef FRED
    if (t == 0) {
        float pw = sTN / fmaxf(sTP, 1e-8f);
        out[0] = -(pw*sA + sB);
        out[1] = sP; out[2] = sN; out[3] = sTP; out[4] = sTN;
    }
}

extern "C" void kernel_launch(void* const* d_in, const int* in_sizes, int n_in,
                              void* d_out, int out_size, void* d_ws, size_t ws_size,
                              hipStream_t stream) {
    const float* pt        = (const float*)d_in[0];
    const float* init_tab  = (const float*)d_in[1];
    const float* sine_tab  = (const float*)d_in[2];
    const float* W1        = (const float*)d_in[3];
    const float* b1        = (const float*)d_in[4];
    const float* t1        = (const float*)d_in[5];
    const float* W2        = (const float*)d_in[6];
    const float* b2        = (const float*)d_in[7];
    const float* w_eval    = (const float*)d_in[8];
    const float* b_eval    = (const float*)d_in[9];
    const float* t_eval    = (const float*)d_in[10];
    const float* pos       = (const float*)d_in[11];
    const float* neg       = (const float*)d_in[12];
    const int*   init_thax = (const int*)d_in[13];
    const int*   init_sine = (const int*)d_in[14];
    const int*   drule     = (const int*)d_in[15];
    const int*   dparents  = (const int*)d_in[16];
    const int*   labeled   = (const int*)d_in[17];
    float* out = (float*)d_out;

    // workspace layout (bytes, all 16-aligned)
    char* w = (char*)d_ws;
    const size_t STORE_B = (size_t)NTOT * D_ * 4;            // 75,497,472
    const size_t SORT_B  = (size_t)LL * MP * 4;              //    278,528
    const size_t P1_B    = (size_t)R_*KS1*NT*64*8*2;         //  2,097,152
    const size_t P2_B    = (size_t)R_*KS2*NT*64*8*2;         //  1,048,576
    float*  store    = (float*) w;                    w += STORE_B;
    int*    sorted   = (int*)   w;                    w += SORT_B;
    ushort* P1h      = (ushort*)w;                    w += P1_B;
    ushort* P2h      = (ushort*)w;                    w += P2_B;
    float*  partials = (float*) w;                    // NPART*6*4 = 101,376

    prep_kernel<<<PREP_BLKS, 256, 0, stream>>>(drule, sorted, init_tab, sine_tab,
                                               init_thax, init_sine, store,
                                               W1, P1h, W2, P2h,
                                               w_eval, b_eval, t_eval, pt,
                                               pos, neg, labeled, partials);
    for (int l = 0; l < LL; l++)
        layer_kernel<<<NB, 1024, 0, stream>>>(store, sorted, drule, dparents,
                                              P1h, P2h, b1, t1, b2, pt,
                                              w_eval, b_eval, t_eval,
                                              pos, neg, labeled, partials, l);
    final_kernel<<<1, 256, 0, stream>>>(partials, out);
}